// Round 1
// baseline (13788.748 us; speedup 1.0000x reference)
//
#include <hip/hip_runtime.h>

// Problem constants
#define Bb 128
#define Tt 512
#define Dd 1024
#define Hh 1024
#define KC 2048   // D + H (concatenated K)
#define NG 4096   // 4*H, gate-interleaved columns: n = 4*j + gate

// Step-GEMM tiling
#define BM 32
#define BN 64
#define BK 64

typedef __attribute__((ext_vector_type(4))) float f32x4;
typedef __attribute__((ext_vector_type(8))) short s16x8;

__device__ inline unsigned short f2bf(float f) {
  union { float f; unsigned int u; } x;
  x.f = f;
  unsigned int r = x.u + 0x7fffu + ((x.u >> 16) & 1u);  // RNE
  return (unsigned short)(r >> 16);
}

// Build Wr [NG][KC] bf16 (gate-interleaved rows, K = [W_ih | W_hh]),
// reordered bias br [NG], zero cell state c [B*H].
__global__ void prep_kernel(const float* __restrict__ Wih,
                            const float* __restrict__ Whh,
                            const float* __restrict__ bias,
                            unsigned short* __restrict__ Wr,
                            float* __restrict__ br,
                            float* __restrict__ c) {
  long tid0 = (long)blockIdx.x * blockDim.x + threadIdx.x;
  long stride = (long)gridDim.x * blockDim.x;
  const long total = (long)NG * KC;
  for (long idx = tid0; idx < total; idx += stride) {
    int n = (int)(idx >> 11);        // / KC
    int k = (int)(idx & (KC - 1));   // % KC
    int j = n >> 2, g = n & 3;
    float v;
    if (k < Dd) v = Wih[(size_t)(g * Hh + j) * Dd + k];
    else        v = Whh[(size_t)(g * Hh + j) * Hh + (k - Dd)];
    Wr[idx] = f2bf(v);
  }
  for (long idx = tid0; idx < NG; idx += stride) {
    int j = (int)idx >> 2, g = (int)idx & 3;
    br[idx] = bias[g * Hh + j];
  }
  for (long idx = tid0; idx < (long)Bb * Hh; idx += stride)
    c[idx] = 0.f;
}

// One LSTM timestep: gates = [x_t ; h_prev] @ Wr^T + br, then pointwise.
// Writes h_t to hout, updates c in place.
__global__ __launch_bounds__(256)
void lstm_step(const float* __restrict__ xt,     // x + t*D; row stride T*D
               const float* __restrict__ hprev,  // [B,H] or nullptr (t==0)
               const unsigned short* __restrict__ Wr,  // [NG][KC] bf16 bits
               const float* __restrict__ br,     // [NG]
               float* __restrict__ c,            // [B,H] in/out
               float* __restrict__ hout) {       // [B,H]
  __shared__ unsigned short As[BM][BK + 8];
  __shared__ unsigned short Bs[BN][BK + 8];
  __shared__ float Gs[BM][BN];

  const int tid = threadIdx.x;
  const int lane = tid & 63;
  const int wid = tid >> 6;
  const int wr = wid >> 1;   // 0..1 : 16-row slice
  const int wc = wid & 1;    // 0..1 : 32-col slice
  const int m0 = blockIdx.x * BM;
  const int n0 = blockIdx.y * BN;

  f32x4 acc0 = {0.f, 0.f, 0.f, 0.f};
  f32x4 acc1 = {0.f, 0.f, 0.f, 0.f};

  // staging decomposition
  const int a_row = tid >> 3;        // 0..31, 8 threads per row
  const int a_k = (tid & 7) << 3;    // 8 floats each
  const int b_row = tid >> 2;        // 0..63, 4 threads per row
  const int b_k = (tid & 3) << 4;    // 16 bf16 each

  for (int kc = 0; kc < KC; kc += BK) {
    // ---- stage A tile (fp32 -> bf16): rows of [x_t ; h_prev] ----
    {
      int k = kc + a_k;
      float v[8];
      if (k < Dd) {
        const float4* s =
            (const float4*)(xt + (size_t)(m0 + a_row) * ((size_t)Tt * Dd) + k);
        float4 p0 = s[0], p1 = s[1];
        v[0] = p0.x; v[1] = p0.y; v[2] = p0.z; v[3] = p0.w;
        v[4] = p1.x; v[5] = p1.y; v[6] = p1.z; v[7] = p1.w;
      } else if (hprev) {
        const float4* s =
            (const float4*)(hprev + (size_t)(m0 + a_row) * Hh + (k - Dd));
        float4 p0 = s[0], p1 = s[1];
        v[0] = p0.x; v[1] = p0.y; v[2] = p0.z; v[3] = p0.w;
        v[4] = p1.x; v[5] = p1.y; v[6] = p1.z; v[7] = p1.w;
      } else {
#pragma unroll
        for (int e = 0; e < 8; e++) v[e] = 0.f;
      }
#pragma unroll
      for (int e = 0; e < 8; e++) As[a_row][a_k + e] = f2bf(v[e]);
    }
    // ---- stage B tile: Wr rows (already bf16) ----
    {
      const uint4* s = (const uint4*)(Wr + (size_t)(n0 + b_row) * KC + kc + b_k);
      uint4 p0 = s[0], p1 = s[1];
      *(uint4*)&Bs[b_row][b_k] = p0;
      *(uint4*)&Bs[b_row][b_k + 8] = p1;
    }
    __syncthreads();

#pragma unroll
    for (int ks = 0; ks < BK; ks += 32) {
      // A frag: row = lane&15, k-block = lane>>4 (8 contiguous k)
      s16x8 af = *(const s16x8*)&As[wr * 16 + (lane & 15)][ks + ((lane >> 4) << 3)];
      s16x8 bf0 = *(const s16x8*)&Bs[wc * 32 + (lane & 15)][ks + ((lane >> 4) << 3)];
      s16x8 bf1 = *(const s16x8*)&Bs[wc * 32 + 16 + (lane & 15)][ks + ((lane >> 4) << 3)];
      acc0 = __builtin_amdgcn_mfma_f32_16x16x32_bf16(af, bf0, acc0, 0, 0, 0);
      acc1 = __builtin_amdgcn_mfma_f32_16x16x32_bf16(af, bf1, acc1, 0, 0, 0);
    }
    __syncthreads();
  }

  // ---- dump accumulators to LDS gate tile ----
  // C/D frag layout (m89-verified): col = lane&15, row = (lane>>4)*4 + reg
  {
    int colb = wc * 32 + (lane & 15);
    int rbase = wr * 16 + ((lane >> 4) << 2);
#pragma unroll
    for (int r = 0; r < 4; r++) Gs[rbase + r][colb] = acc0[r];
#pragma unroll
    for (int r = 0; r < 4; r++) Gs[rbase + r][colb + 16] = acc1[r];
  }
  __syncthreads();

  // ---- LSTM pointwise: 32 rows x 16 hidden cols per tile ----
  for (int e = tid; e < BM * (BN / 4); e += 256) {
    int row = e >> 4;      // 0..31
    int jc = e & 15;       // 0..15
    int gi = jc << 2;
    float iv = Gs[row][gi + 0] + br[n0 + gi + 0];
    float fv = Gs[row][gi + 1] + br[n0 + gi + 1];
    float gv = Gs[row][gi + 2] + br[n0 + gi + 2];
    float ov = Gs[row][gi + 3] + br[n0 + gi + 3];
    int gb = m0 + row;               // batch index
    int j = (n0 >> 2) + jc;          // hidden index
    float cv = c[(size_t)gb * Hh + j];
    float ig = 1.f / (1.f + __expf(-iv));
    float fg = 1.f / (1.f + __expf(-fv));
    float og = 1.f / (1.f + __expf(-ov));
    float gg = tanhf(gv);
    float cn = fg * cv + ig * gg;
    float hn = og * tanhf(cn);
    c[(size_t)gb * Hh + j] = cn;
    hout[(size_t)gb * Hh + j] = hn;
  }
}

__global__ void finalize_kernel(const float* __restrict__ hlast,
                                const float* __restrict__ c,
                                float* __restrict__ dh,
                                float* __restrict__ dc) {
  int i = blockIdx.x * 256 + threadIdx.x;
  if (i < Bb * Hh) {
    dh[i] = hlast[i];
    dc[i] = c[i];
  }
}

extern "C" void kernel_launch(void* const* d_in, const int* in_sizes, int n_in,
                              void* d_out, int out_size, void* d_ws, size_t ws_size,
                              hipStream_t stream) {
  const float* x = (const float*)d_in[0];     // [B,T,D]
  const float* Wih = (const float*)d_in[1];   // [4H,D]
  const float* Whh = (const float*)d_in[2];   // [4H,H]
  const float* bias = (const float*)d_in[3];  // [4H]
  float* out = (float*)d_out;                 // [T,B,H] ++ [B,H] ++ [B,H]

  char* ws = (char*)d_ws;
  unsigned short* Wr = (unsigned short*)ws;                       // 16 MB
  float* br = (float*)(ws + (size_t)NG * KC * 2);                 // 16 KB
  float* c = (float*)(ws + (size_t)NG * KC * 2 + (size_t)NG * 4); // 512 KB

  prep_kernel<<<1024, 256, 0, stream>>>(Wih, Whh, bias, Wr, br, c);

  dim3 grid(Bb / BM, NG / BN);  // 4 x 64 = 256 workgroups
  for (int t = 0; t < Tt; t++) {
    const float* xt = x + (size_t)t * Dd;
    const float* hp = (t == 0) ? nullptr : out + (size_t)(t - 1) * Bb * Hh;
    lstm_step<<<grid, 256, 0, stream>>>(xt, hp, Wr, br, c,
                                        out + (size_t)t * Bb * Hh);
  }

  float* dh = out + (size_t)Tt * Bb * Hh;
  finalize_kernel<<<(Bb * Hh + 255) / 256, 256, 0, stream>>>(
      out + (size_t)(Tt - 1) * Bb * Hh, c, dh, dh + (size_t)Bb * Hh);
}

// Round 2
// 6235.704 us; speedup vs baseline: 2.2113x; 2.2113x over previous
//
#include <hip/hip_runtime.h>

// Problem constants
#define Bb 128
#define Tt 512
#define Dd 1024
#define Hh 1024
#define KC 2048   // D + H (old path)
#define NG 4096   // 4*H, gate-interleaved: n = 4*j + g

typedef __attribute__((ext_vector_type(4))) float f32x4;
typedef __attribute__((ext_vector_type(8))) short s16x8;

__device__ inline unsigned short f2bf(float f) {
  union { float f; unsigned int u; } x;
  x.f = f;
  unsigned int r = x.u + 0x7fffu + ((x.u >> 16) & 1u);  // RNE
  return (unsigned short)(r >> 16);
}
__device__ inline float bf2f(unsigned short u) {
  union { unsigned int u; float f; } x;
  x.u = ((unsigned int)u) << 16;
  return x.f;
}
// async 16B global -> LDS (wave-uniform LDS base + lane*16 HW scatter)
__device__ __forceinline__ void gl_lds16(void* lds, const void* g) {
  __builtin_amdgcn_global_load_lds(
      (const __attribute__((address_space(1))) unsigned int*)g,
      (__attribute__((address_space(3))) unsigned int*)lds, 16, 0, 0);
}

// ============================== NEW PATH =====================================

// Build gate-interleaved bf16 W_ih / W_hh, reordered bias, zero c and h-carrier.
__global__ void prep_new(const float* __restrict__ Wih,
                         const float* __restrict__ Whh,
                         const float* __restrict__ bias,
                         unsigned short* __restrict__ Wihr,
                         unsigned short* __restrict__ Whhr,
                         float* __restrict__ br,
                         float* __restrict__ c,
                         unsigned short* __restrict__ hbf0) {
  long tid0 = (long)blockIdx.x * blockDim.x + threadIdx.x;
  long stride = (long)gridDim.x * blockDim.x;
  const long wtot = (long)NG * 1024;
  for (long i = tid0; i < wtot; i += stride) {
    int n = (int)(i >> 10), k = (int)(i & 1023);
    int j = n >> 2, g = n & 3;
    Wihr[i] = f2bf(Wih[(size_t)(g * Hh + j) * Dd + k]);
    Whhr[i] = f2bf(Whh[(size_t)(g * Hh + j) * Hh + k]);
  }
  for (long i = tid0; i < NG; i += stride) {
    int j = (int)i >> 2, g = (int)i & 3;
    br[i] = bias[g * Hh + j];
  }
  for (long i = tid0; i < (long)Bb * Hh; i += stride) {
    c[i] = 0.f;
    hbf0[i] = 0;
  }
}

// xp[t*B + b][n] = (X @ Wihr^T), bf16 out. M=65536 (row = b*T+t), N=4096, K=1024.
// 128x128 tile, BK=64, 4 waves (2x2 of 64x64). B via global_load_lds w/
// pre-swizzled source; A reg-staged f32->bf16 with swizzled ds_write.
__global__ __launch_bounds__(256)
void xproj_gemm(const float* __restrict__ X,
                const unsigned short* __restrict__ Wr,
                unsigned short* __restrict__ xp) {
  __shared__ unsigned short As[128 * 64];
  __shared__ unsigned short Bs[128 * 64];
  const int tid = threadIdx.x;
  const int lane = tid & 63, wave = tid >> 6;
  const int wr = wave >> 1, wc = wave & 1;

  // bijective XCD swizzle (16384 % 8 == 0): contiguous id2 chunk per XCD,
  // bn-fast so concurrent blocks on an XCD share the A panel in L2.
  int bid = blockIdx.x;
  int id2 = (bid & 7) * (16384 / 8) + (bid >> 3);
  const int m0 = (id2 >> 5) * 128;
  const int n0 = (id2 & 31) * 128;

  f32x4 acc[4][4];
#pragma unroll
  for (int m = 0; m < 4; m++)
#pragma unroll
    for (int n = 0; n < 4; n++) acc[m][n] = (f32x4){0.f, 0.f, 0.f, 0.f};

  const int arow = tid >> 1, ahalf = tid & 1;
  const float* abase = X + (size_t)(m0 + arow) * 1024 + ahalf * 32;

  for (int kc = 0; kc < 1024; kc += 64) {
    // ---- B tile [128 rows][64 bf16]: 16 x 1KB chunks, 4 per wave ----
#pragma unroll
    for (int r = 0; r < 4; r++) {
      int ch = wave * 4 + r;
      int row = ch * 8 + (lane >> 3);          // 8 rows per chunk (128B rows)
      int slot = (lane & 7) ^ (row & 7);       // pre-swizzled source slot
      gl_lds16((char*)Bs + ch * 1024,
               Wr + (size_t)(n0 + row) * 1024 + kc + slot * 8);
    }
    // ---- A tile: each thread 32 floats of one row-half ----
    float4 av[8];
    const float4* asrc = (const float4*)(abase + kc);
#pragma unroll
    for (int i = 0; i < 8; i++) av[i] = asrc[i];
    unsigned short ab[32];
#pragma unroll
    for (int i = 0; i < 8; i++) {
      ab[i * 4 + 0] = f2bf(av[i].x);
      ab[i * 4 + 1] = f2bf(av[i].y);
      ab[i * 4 + 2] = f2bf(av[i].z);
      ab[i * 4 + 3] = f2bf(av[i].w);
    }
#pragma unroll
    for (int i = 0; i < 4; i++) {
      int slot = (ahalf * 4 + i) ^ (arow & 7);
      *(uint4*)((char*)As + arow * 128 + slot * 16) = *(const uint4*)&ab[i * 8];
    }
    __syncthreads();
#pragma unroll
    for (int ks = 0; ks < 2; ks++) {
      s16x8 af[4], bfr[4];
#pragma unroll
      for (int m = 0; m < 4; m++) {
        int row = wr * 64 + m * 16 + (lane & 15);
        int slot = (ks * 4 + (lane >> 4)) ^ (row & 7);
        af[m] = *(const s16x8*)((const char*)As + row * 128 + slot * 16);
      }
#pragma unroll
      for (int n = 0; n < 4; n++) {
        int row = wc * 64 + n * 16 + (lane & 15);
        int slot = (ks * 4 + (lane >> 4)) ^ (row & 7);
        bfr[n] = *(const s16x8*)((const char*)Bs + row * 128 + slot * 16);
      }
#pragma unroll
      for (int m = 0; m < 4; m++)
#pragma unroll
        for (int n = 0; n < 4; n++)
          acc[m][n] = __builtin_amdgcn_mfma_f32_16x16x32_bf16(af[m], bfr[n],
                                                              acc[m][n], 0, 0, 0);
    }
    __syncthreads();
  }

  // epilogue: C/D layout col=lane&15, row=(lane>>4)*4+reg; gemm row = b*T+t
#pragma unroll
  for (int m = 0; m < 4; m++) {
#pragma unroll
    for (int r = 0; r < 4; r++) {
      int gm = m0 + wr * 64 + m * 16 + ((lane >> 4) << 2) + r;
      int t = gm & (Tt - 1), b = gm >> 9;
      unsigned short* dst =
          xp + ((size_t)t * Bb + b) * NG + n0 + wc * 64 + (lane & 15);
#pragma unroll
      for (int n = 0; n < 4; n++) dst[n * 16] = f2bf(acc[m][n][r]);
    }
  }
}

// One timestep, K=1024 recurrence only: gates = hprev @ Whhr^T + xp[t] + br.
// A,B both bf16 via global_load_lds, XOR-swizzled. Tile 32x64, BK=128.
__global__ __launch_bounds__(256)
void lstm_step2(const unsigned short* __restrict__ hp,    // [128][1024] bf16
                const unsigned short* __restrict__ Whhr,  // [4096][1024] bf16
                const float* __restrict__ br,             // [4096]
                const unsigned short* __restrict__ xpt,   // [128][4096] bf16
                float* __restrict__ c,                    // [128][1024]
                float* __restrict__ hout,                 // [128][1024] f32
                unsigned short* __restrict__ hnext) {     // [128][1024] bf16
  __shared__ unsigned short As[32 * 128];
  __shared__ unsigned short Bs[64 * 128];
  __shared__ float Gs[32][68];

  const int tid = threadIdx.x;
  const int lane = tid & 63, wave = tid >> 6;
  const int wr = wave >> 1, wc = wave & 1;

  // XCD swizzle: 8 consecutive by-slices per XCD -> W_hh slice stays in its L2
  int lid = blockIdx.x;
  int xcd = lid & 7, slt = lid >> 3;
  const int by = xcd * 8 + (slt >> 2);
  const int bx = slt & 3;
  const int m0 = bx * 32, n0 = by * 64;

  f32x4 acc0 = {0.f, 0.f, 0.f, 0.f};
  f32x4 acc1 = {0.f, 0.f, 0.f, 0.f};

  for (int kc = 0; kc < 1024; kc += 128) {
    // A tile [32][128]: 8 x 1KB chunks (4 rows of 256B each), 2 per wave
#pragma unroll
    for (int r = 0; r < 2; r++) {
      int ch = wave * 2 + r;
      int row = ch * 4 + (lane >> 4);
      int slot = (lane & 15) ^ (row & 7);
      gl_lds16((char*)As + ch * 1024,
               hp + (size_t)(m0 + row) * 1024 + kc + slot * 8);
    }
    // B tile [64][128]: 16 x 1KB chunks, 4 per wave
#pragma unroll
    for (int r = 0; r < 4; r++) {
      int ch = wave * 4 + r;
      int row = ch * 4 + (lane >> 4);
      int slot = (lane & 15) ^ (row & 7);
      gl_lds16((char*)Bs + ch * 1024,
               Whhr + (size_t)(n0 + row) * 1024 + kc + slot * 8);
    }
    __syncthreads();
#pragma unroll
    for (int ks = 0; ks < 4; ks++) {
      int colslot = ks * 4 + (lane >> 4);
      s16x8 af, b0, b1;
      {
        int row = wr * 16 + (lane & 15);
        int s = colslot ^ (row & 7);
        af = *(const s16x8*)((const char*)As + row * 256 + s * 16);
      }
      {
        int row = wc * 32 + (lane & 15);
        int s = colslot ^ (row & 7);
        b0 = *(const s16x8*)((const char*)Bs + row * 256 + s * 16);
      }
      {
        int row = wc * 32 + 16 + (lane & 15);
        int s = colslot ^ (row & 7);
        b1 = *(const s16x8*)((const char*)Bs + row * 256 + s * 16);
      }
      acc0 = __builtin_amdgcn_mfma_f32_16x16x32_bf16(af, b0, acc0, 0, 0, 0);
      acc1 = __builtin_amdgcn_mfma_f32_16x16x32_bf16(af, b1, acc1, 0, 0, 0);
    }
    __syncthreads();
  }

  // dump accumulators (col=lane&15, row=(lane>>4)*4+reg)
  {
    int colb = wc * 32 + (lane & 15);
    int rbase = wr * 16 + ((lane >> 4) << 2);
#pragma unroll
    for (int r = 0; r < 4; r++) Gs[rbase + r][colb] = acc0[r];
#pragma unroll
    for (int r = 0; r < 4; r++) Gs[rbase + r][colb + 16] = acc1[r];
  }
  __syncthreads();

  // pointwise LSTM: 32 rows x 16 hidden units
  for (int e = tid; e < 512; e += 256) {
    int row = e >> 4, jc = e & 15;
    int gi = jc << 2;
    const unsigned short* xv = xpt + (size_t)(m0 + row) * NG + n0 + gi;
    float4 bv = *(const float4*)(br + n0 + gi);
    float iv = Gs[row][gi + 0] + bf2f(xv[0]) + bv.x;
    float fv = Gs[row][gi + 1] + bf2f(xv[1]) + bv.y;
    float gv = Gs[row][gi + 2] + bf2f(xv[2]) + bv.z;
    float ov = Gs[row][gi + 3] + bf2f(xv[3]) + bv.w;
    int gb = m0 + row;
    int j = (n0 >> 2) + jc;
    size_t ci = (size_t)gb * Hh + j;
    float cv = c[ci];
    float ig = 1.f / (1.f + __expf(-iv));
    float fg = 1.f / (1.f + __expf(-fv));
    float og = 1.f / (1.f + __expf(-ov));
    float gg = tanhf(gv);
    float cn = fg * cv + ig * gg;
    float hn = og * tanhf(cn);
    c[ci] = cn;
    hout[ci] = hn;
    hnext[ci] = f2bf(hn);
  }
}

__global__ void finalize_kernel(const float* __restrict__ hlast,
                                const float* __restrict__ c,
                                float* __restrict__ dh,
                                float* __restrict__ dc) {
  int i = blockIdx.x * 256 + threadIdx.x;
  if (i < Bb * Hh) {
    dh[i] = hlast[i];
    dc[i] = c[i];
  }
}

// ====================== OLD PATH (fallback, ws-limited) ======================

__global__ void prep_kernel(const float* __restrict__ Wih,
                            const float* __restrict__ Whh,
                            const float* __restrict__ bias,
                            unsigned short* __restrict__ Wr,
                            float* __restrict__ br,
                            float* __restrict__ c) {
  long tid0 = (long)blockIdx.x * blockDim.x + threadIdx.x;
  long stride = (long)gridDim.x * blockDim.x;
  const long total = (long)NG * KC;
  for (long idx = tid0; idx < total; idx += stride) {
    int n = (int)(idx >> 11);
    int k = (int)(idx & (KC - 1));
    int j = n >> 2, g = n & 3;
    float v;
    if (k < Dd) v = Wih[(size_t)(g * Hh + j) * Dd + k];
    else        v = Whh[(size_t)(g * Hh + j) * Hh + (k - Dd)];
    Wr[idx] = f2bf(v);
  }
  for (long idx = tid0; idx < NG; idx += stride) {
    int j = (int)idx >> 2, g = (int)idx & 3;
    br[idx] = bias[g * Hh + j];
  }
  for (long idx = tid0; idx < (long)Bb * Hh; idx += stride)
    c[idx] = 0.f;
}

__global__ __launch_bounds__(256)
void lstm_step(const float* __restrict__ xt,
               const float* __restrict__ hprev,
               const unsigned short* __restrict__ Wr,
               const float* __restrict__ br,
               float* __restrict__ c,
               float* __restrict__ hout) {
  __shared__ unsigned short As2[32][64 + 8];
  __shared__ unsigned short Bs2[64][64 + 8];
  __shared__ float Gs[32][64];

  const int tid = threadIdx.x;
  const int lane = tid & 63;
  const int wid = tid >> 6;
  const int wr = wid >> 1;
  const int wc = wid & 1;
  const int m0 = blockIdx.x * 32;
  const int n0 = blockIdx.y * 64;

  f32x4 acc0 = {0.f, 0.f, 0.f, 0.f};
  f32x4 acc1 = {0.f, 0.f, 0.f, 0.f};

  const int a_row = tid >> 3;
  const int a_k = (tid & 7) << 3;
  const int b_row = tid >> 2;
  const int b_k = (tid & 3) << 4;

  for (int kc = 0; kc < KC; kc += 64) {
    {
      int k = kc + a_k;
      float v[8];
      if (k < Dd) {
        const float4* s =
            (const float4*)(xt + (size_t)(m0 + a_row) * ((size_t)Tt * Dd) + k);
        float4 p0 = s[0], p1 = s[1];
        v[0] = p0.x; v[1] = p0.y; v[2] = p0.z; v[3] = p0.w;
        v[4] = p1.x; v[5] = p1.y; v[6] = p1.z; v[7] = p1.w;
      } else if (hprev) {
        const float4* s =
            (const float4*)(hprev + (size_t)(m0 + a_row) * Hh + (k - Dd));
        float4 p0 = s[0], p1 = s[1];
        v[0] = p0.x; v[1] = p0.y; v[2] = p0.z; v[3] = p0.w;
        v[4] = p1.x; v[5] = p1.y; v[6] = p1.z; v[7] = p1.w;
      } else {
#pragma unroll
        for (int e = 0; e < 8; e++) v[e] = 0.f;
      }
#pragma unroll
      for (int e = 0; e < 8; e++) As2[a_row][a_k + e] = f2bf(v[e]);
    }
    {
      const uint4* s = (const uint4*)(Wr + (size_t)(n0 + b_row) * KC + kc + b_k);
      uint4 p0 = s[0], p1 = s[1];
      *(uint4*)&Bs2[b_row][b_k] = p0;
      *(uint4*)&Bs2[b_row][b_k + 8] = p1;
    }
    __syncthreads();
#pragma unroll
    for (int ks = 0; ks < 64; ks += 32) {
      s16x8 af = *(const s16x8*)&As2[wr * 16 + (lane & 15)][ks + ((lane >> 4) << 3)];
      s16x8 bf0 = *(const s16x8*)&Bs2[wc * 32 + (lane & 15)][ks + ((lane >> 4) << 3)];
      s16x8 bf1 = *(const s16x8*)&Bs2[wc * 32 + 16 + (lane & 15)][ks + ((lane >> 4) << 3)];
      acc0 = __builtin_amdgcn_mfma_f32_16x16x32_bf16(af, bf0, acc0, 0, 0, 0);
      acc1 = __builtin_amdgcn_mfma_f32_16x16x32_bf16(af, bf1, acc1, 0, 0, 0);
    }
    __syncthreads();
  }

  {
    int colb = wc * 32 + (lane & 15);
    int rbase = wr * 16 + ((lane >> 4) << 2);
#pragma unroll
    for (int r = 0; r < 4; r++) Gs[rbase + r][colb] = acc0[r];
#pragma unroll
    for (int r = 0; r < 4; r++) Gs[rbase + r][colb + 16] = acc1[r];
  }
  __syncthreads();

  for (int e = tid; e < 512; e += 256) {
    int row = e >> 4;
    int jc = e & 15;
    int gi = jc << 2;
    float iv = Gs[row][gi + 0] + br[n0 + gi + 0];
    float fv = Gs[row][gi + 1] + br[n0 + gi + 1];
    float gv = Gs[row][gi + 2] + br[n0 + gi + 2];
    float ov = Gs[row][gi + 3] + br[n0 + gi + 3];
    int gb = m0 + row;
    int j = (n0 >> 2) + jc;
    float cv = c[(size_t)gb * Hh + j];
    float ig = 1.f / (1.f + __expf(-iv));
    float fg = 1.f / (1.f + __expf(-fv));
    float og = 1.f / (1.f + __expf(-ov));
    float gg = tanhf(gv);
    float cn = fg * cv + ig * gg;
    float hn = og * tanhf(cn);
    c[(size_t)gb * Hh + j] = cn;
    hout[(size_t)gb * Hh + j] = hn;
  }
}

// ============================== LAUNCHER =====================================

extern "C" void kernel_launch(void* const* d_in, const int* in_sizes, int n_in,
                              void* d_out, int out_size, void* d_ws, size_t ws_size,
                              hipStream_t stream) {
  const float* x = (const float*)d_in[0];     // [B,T,D]
  const float* Wih = (const float*)d_in[1];   // [4H,D]
  const float* Whh = (const float*)d_in[2];   // [4H,H]
  const float* bias = (const float*)d_in[3];  // [4H]
  float* out = (float*)d_out;                 // [T,B,H] ++ [B,H] ++ [B,H]
  char* ws = (char*)d_ws;

  const size_t WHH_OFF = 0;
  const size_t WIH_OFF = 8ull << 20;
  const size_t BR_OFF = 16ull << 20;
  const size_t C_OFF = (16ull << 20) + (64ull << 10);
  const size_t H0_OFF = 17ull << 20;
  const size_t H1_OFF = (17ull << 20) + (256ull << 10);
  const size_t XP_OFF = 18ull << 20;
  const size_t NEED = XP_OFF + (size_t)Tt * Bb * NG * 2;  // ~530 MB

  if (ws_size >= NEED) {
    unsigned short* Whhr = (unsigned short*)(ws + WHH_OFF);
    unsigned short* Wihr = (unsigned short*)(ws + WIH_OFF);
    float* br = (float*)(ws + BR_OFF);
    float* c = (float*)(ws + C_OFF);
    unsigned short* hb0 = (unsigned short*)(ws + H0_OFF);
    unsigned short* hb1 = (unsigned short*)(ws + H1_OFF);
    unsigned short* xp = (unsigned short*)(ws + XP_OFF);

    prep_new<<<2048, 256, 0, stream>>>(Wih, Whh, bias, Wihr, Whhr, br, c, hb0);
    xproj_gemm<<<16384, 256, 0, stream>>>(x, Wihr, xp);
    for (int t = 0; t < Tt; t++) {
      unsigned short* hin = (t & 1) ? hb1 : hb0;
      unsigned short* hnx = (t & 1) ? hb0 : hb1;
      lstm_step2<<<256, 256, 0, stream>>>(hin, Whhr, br,
                                          xp + (size_t)t * Bb * NG, c,
                                          out + (size_t)t * Bb * Hh, hnx);
    }
    float* dh = out + (size_t)Tt * Bb * Hh;
    finalize_kernel<<<(Bb * Hh + 255) / 256, 256, 0, stream>>>(
        out + (size_t)(Tt - 1) * Bb * Hh, c, dh, dh + (size_t)Bb * Hh);
  } else {
    // fallback: round-1 path (16.5 MB ws)
    unsigned short* Wr = (unsigned short*)ws;
    float* br = (float*)(ws + (size_t)NG * KC * 2);
    float* c = (float*)(ws + (size_t)NG * KC * 2 + (size_t)NG * 4);

    prep_kernel<<<1024, 256, 0, stream>>>(Wih, Whh, bias, Wr, br, c);
    dim3 grid(Bb / 32, NG / 64);
    for (int t = 0; t < Tt; t++) {
      const float* xt = x + (size_t)t * Dd;
      const float* hp = (t == 0) ? nullptr : out + (size_t)(t - 1) * Bb * Hh;
      lstm_step<<<grid, 256, 0, stream>>>(xt, hp, Wr, br, c,
                                          out + (size_t)t * Bb * Hh);
    }
    float* dh = out + (size_t)Tt * Bb * Hh;
    finalize_kernel<<<(Bb * Hh + 255) / 256, 256, 0, stream>>>(
        out + (size_t)(Tt - 1) * Bb * Hh, c, dh, dh + (size_t)Bb * Hh);
  }
}